// Round 9
// baseline (1088.760 us; speedup 1.0000x reference)
//
#include <hip/hip_runtime.h>
#include <math.h>

#define N_NODES 100000
#define CDIM 128
#define E_EDGES 500000
#define NEG_SLOPE 0.2f
#define SCAN_CHUNK 1024   // 256 threads x 4 items
#define SCAN_NB ((N_NODES + SCAN_CHUNK - 1) / SCAN_CHUNK)   // 98
#define NSTRIP256 ((N_NODES + 255) / 256)                   // 391

typedef __attribute__((ext_vector_type(8))) short short8;             // 8 bf16 (MFMA frag)
typedef __attribute__((ext_vector_type(8))) unsigned short ushort8;
typedef __attribute__((ext_vector_type(4))) unsigned short u16x4;
typedef __attribute__((ext_vector_type(4))) float f32x4;

static __device__ __forceinline__ float bf2f(unsigned short u) {
    unsigned int t = ((unsigned int)u) << 16;
    return __builtin_bit_cast(float, t);
}
static __device__ __forceinline__ unsigned short f2bf(float f) {
    unsigned int u = __builtin_bit_cast(unsigned int, f);
    unsigned int r = (u + 0x7FFFu + ((u >> 16) & 1u)) >> 16;   // RNE
    return (unsigned short)r;
}
static __device__ __forceinline__ int clampi(int v, int hi) {
    return v < 0 ? 0 : (v >= hi ? hi - 1 : v);
}
static __device__ __forceinline__ float lrelu(float v) {
    return v > 0.0f ? v : NEG_SLOPE * v;
}

// ---- pack all 6 fp32 128x128 W into MFMA-fragment-major bf16 ----
// chunk(kk,t): lane l (m=l&15,q=l>>4) owns W[kk*32+q*8+u][t*16+m], u=0..7.
__global__ __launch_bounds__(256)
void pack_w_all(const float* __restrict__ W0, const float* __restrict__ W1,
                const float* __restrict__ W2, const float* __restrict__ W3,
                const float* __restrict__ W4, const float* __restrict__ W5,
                unsigned short* __restrict__ Wf) {
    const float* Wp[6] = {W0, W1, W2, W3, W4, W5};
    int mi  = blockIdx.x >> 3;                       // 0..5 (block-uniform)
    int rem = ((blockIdx.x & 7) << 8) | threadIdx.x; // 0..2047
    const float* W = Wp[mi];
    int l = rem & 63, t = (rem >> 6) & 7, kk = rem >> 9;
    int m = l & 15, q = l >> 4;
    int j = t * 16 + m;
    int k0 = kk * 32 + q * 8;
    ushort8 o;
#pragma unroll
    for (int u = 0; u < 8; ++u) o[u] = f2bf(W[(k0 + u) * 128 + j]);
    *(ushort8*)(Wf + ((size_t)mi * 2048 + rem) * 8) = o;
}

// ---- fused 3-matrix projection, LDS-fed:
// A=bf16(X@Wl), B=bf16(X@Wr), Rb=bf16(X@Wres+bias)
// 1024 threads (16 waves), 96 KB LDS holds all 3 W mats (frag-major) -> K-loop is
// ds_read_b128 + MFMA only. 1 block/CU (LDS-capped) but 16 waves/CU resident.
// a-op = W frag, b-op = X frag -> lane owns out[row0+lane%16][t*16+q*4+r] (wide stores).
// XSPLIT: X fp32 hi/lo split (fp32-accurate). !XSPLIT: X bf16 (half MFMAs).
// Grid-stride over 256-row strips (grid 196 x 2 strips = balanced single round).
template <bool XSPLIT>
__global__ __launch_bounds__(1024)
void projF(const void* __restrict__ Xv,
           const unsigned short* __restrict__ Wf,    // 3 mats, frag-major
           const float* __restrict__ bias,
           unsigned short* __restrict__ Aout,
           unsigned short* __restrict__ Bout,
           unsigned short* __restrict__ Rbout, int n_rows) {
    __shared__ unsigned short wlds[49152];   // 96 KB = 3 mats x 16384 shorts
    const int tid = threadIdx.x;
#pragma unroll
    for (int it = 0; it < 6; ++it) {
        int i = it * 1024 + tid;             // 6144 chunks of 8 shorts
        *(ushort8*)(wlds + (size_t)i * 8) = *(const ushort8*)(Wf + (size_t)i * 8);
    }
    __syncthreads();

    const int wave = tid >> 6;
    const int lane = tid & 63;
    const int m = lane & 15, q = lane >> 4;

    for (int strip = blockIdx.x; strip < NSTRIP256; strip += gridDim.x) {
        const int row0 = strip * 256 + wave * 16;
        const int xrow = row0 + m;                     // this lane's output row
        const int arow = xrow < n_rows ? xrow : n_rows - 1;

        f32x4 acc[3][8];
#pragma unroll
        for (int mi = 0; mi < 3; ++mi)
#pragma unroll
            for (int t = 0; t < 8; ++t) acc[mi][t] = (f32x4)0.0f;

#pragma unroll
        for (int kk = 0; kk < 4; ++kk) {
            short8 xh, xl_;
            if (XSPLIT) {
                const float* xp = (const float*)Xv + (size_t)arow * CDIM + kk * 32 + q * 8;
                f32x4 x0 = *(const f32x4*)xp;
                f32x4 x1 = *(const f32x4*)(xp + 4);
#pragma unroll
                for (int j = 0; j < 4; ++j) {
                    unsigned short h0 = f2bf(x0[j]);
                    xh[j] = (short)h0;
                    xl_[j] = (short)f2bf(x0[j] - bf2f(h0));
                    unsigned short h1 = f2bf(x1[j]);
                    xh[4 + j] = (short)h1;
                    xl_[4 + j] = (short)f2bf(x1[j] - bf2f(h1));
                }
            } else {
                xh = *(const short8*)((const unsigned short*)Xv +
                                      (size_t)arow * CDIM + kk * 32 + q * 8);
            }
#pragma unroll
            for (int t = 0; t < 8; ++t) {
                const size_t fo = ((size_t)(kk * 8 + t) * 64 + lane) * 8;
                short8 w0 = *(const short8*)(wlds + fo);
                short8 w1 = *(const short8*)(wlds + 16384 + fo);
                short8 w2 = *(const short8*)(wlds + 32768 + fo);
                acc[0][t] = __builtin_amdgcn_mfma_f32_16x16x32_bf16(w0, xh, acc[0][t], 0, 0, 0);
                acc[1][t] = __builtin_amdgcn_mfma_f32_16x16x32_bf16(w1, xh, acc[1][t], 0, 0, 0);
                acc[2][t] = __builtin_amdgcn_mfma_f32_16x16x32_bf16(w2, xh, acc[2][t], 0, 0, 0);
                if (XSPLIT) {
                    acc[0][t] = __builtin_amdgcn_mfma_f32_16x16x32_bf16(w0, xl_, acc[0][t], 0, 0, 0);
                    acc[1][t] = __builtin_amdgcn_mfma_f32_16x16x32_bf16(w1, xl_, acc[1][t], 0, 0, 0);
                    acc[2][t] = __builtin_amdgcn_mfma_f32_16x16x32_bf16(w2, xl_, acc[2][t], 0, 0, 0);
                }
            }
        }

        if (xrow < n_rows) {
#pragma unroll
            for (int t = 0; t < 8; ++t) {
                u16x4 oa, ob, orr;
                f32x4 bv = *(const f32x4*)(bias + t * 16 + q * 4);
#pragma unroll
                for (int r = 0; r < 4; ++r) {
                    oa[r] = f2bf(acc[0][t][r]);
                    ob[r] = f2bf(acc[1][t][r]);
                    orr[r] = f2bf(acc[2][t][r] + bv[r]);
                }
                *(u16x4*)(Aout  + (size_t)xrow * CDIM + t * 16 + q * 4) = oa;
                *(u16x4*)(Bout  + (size_t)xrow * CDIM + t * 16 + q * 4) = ob;
                *(u16x4*)(Rbout + (size_t)xrow * CDIM + t * 16 + q * 4) = orr;
            }
        }
    }
}

// ======================= CSR build (once per launch) =======================
__global__ __launch_bounds__(256)
void hist_dst(const int* __restrict__ dst, int* __restrict__ cnt, int n) {
    int e = blockIdx.x * 256 + threadIdx.x;
    if (e < n) atomicAdd(&cnt[clampi(dst[e], N_NODES)], 1);
}

__global__ __launch_bounds__(256)
void scan_local(const int* __restrict__ cnt, int* __restrict__ incl,
                int* __restrict__ blockSums, int n) {
    __shared__ int lds[256];
    int t = threadIdx.x;
    int base = blockIdx.x * SCAN_CHUNK + t * 4;
    int v[4], s = 0;
#pragma unroll
    for (int j = 0; j < 4; ++j) { v[j] = (base + j < n) ? cnt[base + j] : 0; s += v[j]; }
    lds[t] = s;
    __syncthreads();
    for (int off = 1; off < 256; off <<= 1) {
        int x = (t >= off) ? lds[t - off] : 0;
        __syncthreads();
        lds[t] += x;
        __syncthreads();
    }
    int run = lds[t] - s;
#pragma unroll
    for (int j = 0; j < 4; ++j) {
        run += v[j];
        if (base + j < n) incl[base + j] = run;
    }
    if (t == 255) blockSums[blockIdx.x] = lds[255];
}

__global__ __launch_bounds__(128)
void scan_sums(int* __restrict__ blockSums, int nb) {
    __shared__ int lds[128];
    int t = threadIdx.x;
    int v = (t < nb) ? blockSums[t] : 0;
    lds[t] = v;
    __syncthreads();
    for (int off = 1; off < 128; off <<= 1) {
        int x = (t >= off) ? lds[t - off] : 0;
        __syncthreads();
        lds[t] += x;
        __syncthreads();
    }
    if (t < nb) blockSums[t] = lds[t] - v;   // exclusive
}

__global__ __launch_bounds__(256)
void add_offsets(const int* __restrict__ incl, const int* __restrict__ blockSums,
                 const int* __restrict__ cnt, int* __restrict__ rowptr,
                 int* __restrict__ cursor, int n) {
    int i = blockIdx.x * 256 + threadIdx.x;
    if (i < n) {
        int v = incl[i] + blockSums[i / SCAN_CHUNK];
        rowptr[i + 1] = v;
        cursor[i] = v - cnt[i];
    }
    if (i == 0) rowptr[0] = 0;
}

__global__ __launch_bounds__(256)
void scatter_edges(const int* __restrict__ src, const int* __restrict__ dst,
                   int* __restrict__ cursor, int* __restrict__ esrc, int n) {
    int e = blockIdx.x * 256 + threadIdx.x;
    if (e < n) {
        int d = clampi(dst[e], N_NODES);
        int p = atomicAdd(&cursor[d], 1);
        esrc[p] = clampi(src[e], N_NODES);
    }
}

// ======================= fused edge phase =======================
// One wave per dst node; 2 ch/lane. den = sum exp(e); acc = sum exp(e)*xl[src].
// 4-edge unroll: four independent shuffle chains interleaved (latency hiding).
// Epilogue: Out[d] = relu(Rb[d] + acc/den), Rb bf16. BF16OUT: Out bf16 else fp32.
template <bool BF16OUT>
__global__ __launch_bounds__(256)
void fused_edge(const int* __restrict__ rowptr, const int* __restrict__ esrc,
                const unsigned short* __restrict__ A,
                const unsigned short* __restrict__ B,
                const float* __restrict__ att,
                const unsigned short* __restrict__ Rb, void* __restrict__ Outv,
                int n_nodes) {
    const int wave = threadIdx.x >> 6;
    const int lane = threadIdx.x & 63;
    const int d = blockIdx.x * 4 + wave;
    if (d >= n_nodes) return;
    const int c0 = lane * 2;

    unsigned int ub = *(const unsigned int*)(B + (size_t)d * CDIM + c0);
    const float b0 = bf2f((unsigned short)(ub & 0xffff));
    const float b1 = bf2f((unsigned short)(ub >> 16));
    const float at0 = att[c0];
    const float at1 = att[c0 + 1];

    float acc0 = 0.0f, acc1 = 0.0f, den = 0.0f;
    const int p0 = rowptr[d], p1 = rowptr[d + 1];
    int p = p0;
    for (; p + 4 <= p1; p += 4) {
        float a0[4], a1[4], e[4];
#pragma unroll
        for (int u = 0; u < 4; ++u) {
            int s = esrc[p + u];
            unsigned int ua = *(const unsigned int*)(A + (size_t)s * CDIM + c0);
            a0[u] = bf2f((unsigned short)(ua & 0xffff));
            a1[u] = bf2f((unsigned short)(ua >> 16));
            e[u] = lrelu(a0[u] + b0) * at0 + lrelu(a1[u] + b1) * at1;
        }
#pragma unroll
        for (int off = 32; off >= 1; off >>= 1) {
#pragma unroll
            for (int u = 0; u < 4; ++u) e[u] += __shfl_xor(e[u], off, 64);
        }
#pragma unroll
        for (int u = 0; u < 4; ++u) {
            float ee = __expf(fminf(e[u], 60.0f));   // |e| analytically << 60
            den  += ee;
            acc0 += ee * a0[u];
            acc1 += ee * a1[u];
        }
    }
    for (; p < p1; ++p) {
        int s = esrc[p];
        unsigned int ua = *(const unsigned int*)(A + (size_t)s * CDIM + c0);
        float a00 = bf2f((unsigned short)(ua & 0xffff));
        float a01 = bf2f((unsigned short)(ua >> 16));
        float e0 = lrelu(a00 + b0) * at0 + lrelu(a01 + b1) * at1;
#pragma unroll
        for (int off = 32; off >= 1; off >>= 1) e0 += __shfl_xor(e0, off, 64);
        float ee0 = __expf(fminf(e0, 60.0f));
        den  += ee0;
        acc0 += ee0 * a00;
        acc1 += ee0 * a01;
    }

    float inv = 1.0f / fmaxf(den, 1e-16f);
    unsigned int rr = *(const unsigned int*)(Rb + (size_t)d * CDIM + c0);
    float o0 = fmaxf(bf2f((unsigned short)(rr & 0xffff)) + acc0 * inv, 0.0f);
    float o1 = fmaxf(bf2f((unsigned short)(rr >> 16))    + acc1 * inv, 0.0f);
    if (BF16OUT) {
        unsigned int pk = (unsigned int)f2bf(o0) | ((unsigned int)f2bf(o1) << 16);
        *(unsigned int*)((unsigned short*)Outv + (size_t)d * CDIM + c0) = pk;
    } else {
        *(float2*)((float*)Outv + (size_t)d * CDIM + c0) = make_float2(o0, o1);
    }
}

extern "C" void kernel_launch(void* const* d_in, const int* in_sizes, int n_in,
                              void* d_out, int out_size, void* d_ws, size_t ws_size,
                              hipStream_t stream) {
    const float* x     = (const float*)d_in[0];
    const int*   ei    = (const int*)d_in[1];
    const float* Wl1   = (const float*)d_in[2];
    const float* Wr1   = (const float*)d_in[3];
    const float* att1  = (const float*)d_in[4];
    const float* Wres1 = (const float*)d_in[5];
    const float* b1    = (const float*)d_in[6];
    const float* Wl2   = (const float*)d_in[7];
    const float* Wr2   = (const float*)d_in[8];
    const float* att2  = (const float*)d_in[9];
    const float* Wres2 = (const float*)d_in[10];
    const float* b2    = (const float*)d_in[11];

    const int* srcp = ei;
    const int* dstp = ei + E_EDGES;

    // ---- workspace carve (~109 MB) ----
    size_t off = 0;
    char* base = (char*)d_ws;
    auto carve = [&](size_t bytes) -> void* {
        void* q = base + off;
        off += (bytes + 255) & ~(size_t)255;
        return q;
    };
    unsigned short* Wf = (unsigned short*)carve((size_t)6 * 16384 * 2);        // 192 KB
    unsigned short* A  = (unsigned short*)carve((size_t)N_NODES * CDIM * 2);   // 25.6 MB
    unsigned short* B  = (unsigned short*)carve((size_t)N_NODES * CDIM * 2);   // 25.6 MB
    unsigned short* X1 = (unsigned short*)carve((size_t)N_NODES * CDIM * 2);   // 25.6 MB
    unsigned short* Rb = (unsigned short*)carve((size_t)N_NODES * CDIM * 2);   // 25.6 MB
    int* cnt      = (int*)carve((size_t)N_NODES * 4);
    int* rowptr   = (int*)carve((size_t)(N_NODES + 1) * 4);
    int* cursor   = (int*)carve((size_t)N_NODES * 4);
    int* esrc     = (int*)carve((size_t)E_EDGES * 4);
    int* incl     = (int*)carve((size_t)N_NODES * 4);
    int* blockSums= (int*)carve((size_t)SCAN_NB * 4);
    (void)ws_size; (void)n_in; (void)in_sizes; (void)out_size;

    // ---- weight prep: all 6 mats, one launch ----
    pack_w_all<<<48, 256, 0, stream>>>(Wl1, Wr1, Wres1, Wl2, Wr2, Wres2, Wf);

    // ---- CSR build (dst-grouped), reused by both layers ----
    (void)hipMemsetAsync(cnt, 0, (size_t)N_NODES * 4, stream);
    hist_dst<<<(E_EDGES + 255) / 256, 256, 0, stream>>>(dstp, cnt, E_EDGES);
    scan_local<<<SCAN_NB, 256, 0, stream>>>(cnt, incl, blockSums, N_NODES);
    scan_sums<<<1, 128, 0, stream>>>(blockSums, SCAN_NB);
    add_offsets<<<(N_NODES + 255) / 256, 256, 0, stream>>>(incl, blockSums, cnt,
                                                           rowptr, cursor, N_NODES);
    scatter_edges<<<(E_EDGES + 255) / 256, 256, 0, stream>>>(srcp, dstp, cursor,
                                                             esrc, E_EDGES);

    int egrid = (N_NODES + 3) / 4;

    // layer 1: X=x (fp32, split) -> A,B,Rb; fused_edge -> X1 (bf16)
    projF<true ><<<196, 1024, 0, stream>>>(x, Wf, b1, A, B, Rb, N_NODES);
    fused_edge<true ><<<egrid, 256, 0, stream>>>(rowptr, esrc, A, B, att1, Rb, X1, N_NODES);
    // layer 2: X=X1 (bf16, no split) -> A,B,Rb; fused_edge -> d_out (fp32)
    projF<false><<<196, 1024, 0, stream>>>(X1, Wf + (size_t)3 * 16384, b2, A, B, Rb, N_NODES);
    fused_edge<false><<<egrid, 256, 0, stream>>>(rowptr, esrc, A, B, att2, Rb, d_out, N_NODES);
}

// Round 10
// 716.566 us; speedup vs baseline: 1.5194x; 1.5194x over previous
//
#include <hip/hip_runtime.h>
#include <math.h>

#define N_NODES 100000
#define CDIM 128
#define E_EDGES 500000
#define NEG_SLOPE 0.2f
#define SCAN_CHUNK 1024   // 256 threads x 4 items
#define SCAN_NB ((N_NODES + SCAN_CHUNK - 1) / SCAN_CHUNK)   // 98
#define NSTRIP128 ((N_NODES + 127) / 128)                   // 782

typedef __attribute__((ext_vector_type(8))) short short8;             // 8 bf16 (MFMA frag)
typedef __attribute__((ext_vector_type(8))) unsigned short ushort8;
typedef __attribute__((ext_vector_type(4))) unsigned short u16x4;
typedef __attribute__((ext_vector_type(4))) float f32x4;

static __device__ __forceinline__ float bf2f(unsigned short u) {
    unsigned int t = ((unsigned int)u) << 16;
    return __builtin_bit_cast(float, t);
}
static __device__ __forceinline__ unsigned short f2bf(float f) {
    unsigned int u = __builtin_bit_cast(unsigned int, f);
    unsigned int r = (u + 0x7FFFu + ((u >> 16) & 1u)) >> 16;   // RNE
    return (unsigned short)r;
}
static __device__ __forceinline__ int clampi(int v, int hi) {
    return v < 0 ? 0 : (v >= hi ? hi - 1 : v);
}
static __device__ __forceinline__ float lrelu(float v) {
    return v > 0.0f ? v : NEG_SLOPE * v;
}

// ---- pack all 6 fp32 128x128 W into MFMA-fragment-major bf16 ----
// chunk(kk,t): lane l (m=l&15,q=l>>4) owns W[kk*32+q*8+u][t*16+m], u=0..7.
__global__ __launch_bounds__(256)
void pack_w_all(const float* __restrict__ W0, const float* __restrict__ W1,
                const float* __restrict__ W2, const float* __restrict__ W3,
                const float* __restrict__ W4, const float* __restrict__ W5,
                unsigned short* __restrict__ Wf) {
    const float* Wp[6] = {W0, W1, W2, W3, W4, W5};
    int mi  = blockIdx.x >> 3;                       // 0..5 (block-uniform)
    int rem = ((blockIdx.x & 7) << 8) | threadIdx.x; // 0..2047
    const float* W = Wp[mi];
    int l = rem & 63, t = (rem >> 6) & 7, kk = rem >> 9;
    int m = l & 15, q = l >> 4;
    int j = t * 16 + m;
    int k0 = kk * 32 + q * 8;
    ushort8 o;
#pragma unroll
    for (int u = 0; u < 8; ++u) o[u] = f2bf(W[(k0 + u) * 128 + j]);
    *(ushort8*)(Wf + ((size_t)mi * 2048 + rem) * 8) = o;
}

// ---- fused 3-matrix projection, LDS-fed:
// A=bf16(X@Wl), B=bf16(X@Wr), Rb=bf16(X@Wres+bias)
// 512 threads (8 waves), 96 KB LDS holds all 3 W mats (frag-major) -> K-loop is
// ds_read_b128 + MFMA only. 1 block/CU (LDS-capped), 8 waves/CU resident.
// __launch_bounds__(512, 2): min 2 waves/EU -> VGPR cap 256 (kernel ~140, NO SPILL —
// round 9's (1024) default budgeted 64 VGPRs and spilled the accumulators).
// a-op = W frag, b-op = X frag -> lane owns out[row0+lane%16][t*16+q*4+r] (wide stores).
// XSPLIT: X fp32 hi/lo split (fp32-accurate). !XSPLIT: X bf16 (half MFMAs).
// Grid 256, grid-stride over 128-row strips; W staged once per block.
template <bool XSPLIT>
__global__ __launch_bounds__(512, 2)
void projF(const void* __restrict__ Xv,
           const unsigned short* __restrict__ Wf,    // 3 mats, frag-major
           const float* __restrict__ bias,
           unsigned short* __restrict__ Aout,
           unsigned short* __restrict__ Bout,
           unsigned short* __restrict__ Rbout, int n_rows) {
    __shared__ unsigned short wlds[49152];   // 96 KB = 3 mats x 16384 shorts
    const int tid = threadIdx.x;
#pragma unroll
    for (int it = 0; it < 12; ++it) {
        int i = it * 512 + tid;              // 6144 chunks of 8 shorts
        *(ushort8*)(wlds + (size_t)i * 8) = *(const ushort8*)(Wf + (size_t)i * 8);
    }
    __syncthreads();

    const int wave = tid >> 6;               // 0..7
    const int lane = tid & 63;
    const int m = lane & 15, q = lane >> 4;

    for (int strip = blockIdx.x; strip < NSTRIP128; strip += gridDim.x) {
        const int row0 = strip * 128 + wave * 16;
        const int xrow = row0 + m;                     // this lane's output row
        const int arow = xrow < n_rows ? xrow : n_rows - 1;

        f32x4 acc[3][8];
#pragma unroll
        for (int mi = 0; mi < 3; ++mi)
#pragma unroll
            for (int t = 0; t < 8; ++t) acc[mi][t] = (f32x4)0.0f;

#pragma unroll
        for (int kk = 0; kk < 4; ++kk) {
            short8 xh, xl_;
            if (XSPLIT) {
                const float* xp = (const float*)Xv + (size_t)arow * CDIM + kk * 32 + q * 8;
                f32x4 x0 = *(const f32x4*)xp;
                f32x4 x1 = *(const f32x4*)(xp + 4);
#pragma unroll
                for (int j = 0; j < 4; ++j) {
                    unsigned short h0 = f2bf(x0[j]);
                    xh[j] = (short)h0;
                    xl_[j] = (short)f2bf(x0[j] - bf2f(h0));
                    unsigned short h1 = f2bf(x1[j]);
                    xh[4 + j] = (short)h1;
                    xl_[4 + j] = (short)f2bf(x1[j] - bf2f(h1));
                }
            } else {
                xh = *(const short8*)((const unsigned short*)Xv +
                                      (size_t)arow * CDIM + kk * 32 + q * 8);
            }
#pragma unroll
            for (int t = 0; t < 8; ++t) {
                const size_t fo = ((size_t)(kk * 8 + t) * 64 + lane) * 8;
                short8 w0 = *(const short8*)(wlds + fo);
                short8 w1 = *(const short8*)(wlds + 16384 + fo);
                short8 w2 = *(const short8*)(wlds + 32768 + fo);
                acc[0][t] = __builtin_amdgcn_mfma_f32_16x16x32_bf16(w0, xh, acc[0][t], 0, 0, 0);
                acc[1][t] = __builtin_amdgcn_mfma_f32_16x16x32_bf16(w1, xh, acc[1][t], 0, 0, 0);
                acc[2][t] = __builtin_amdgcn_mfma_f32_16x16x32_bf16(w2, xh, acc[2][t], 0, 0, 0);
                if (XSPLIT) {
                    acc[0][t] = __builtin_amdgcn_mfma_f32_16x16x32_bf16(w0, xl_, acc[0][t], 0, 0, 0);
                    acc[1][t] = __builtin_amdgcn_mfma_f32_16x16x32_bf16(w1, xl_, acc[1][t], 0, 0, 0);
                    acc[2][t] = __builtin_amdgcn_mfma_f32_16x16x32_bf16(w2, xl_, acc[2][t], 0, 0, 0);
                }
            }
        }

        if (xrow < n_rows) {
#pragma unroll
            for (int t = 0; t < 8; ++t) {
                u16x4 oa, ob, orr;
                f32x4 bv = *(const f32x4*)(bias + t * 16 + q * 4);
#pragma unroll
                for (int r = 0; r < 4; ++r) {
                    oa[r] = f2bf(acc[0][t][r]);
                    ob[r] = f2bf(acc[1][t][r]);
                    orr[r] = f2bf(acc[2][t][r] + bv[r]);
                }
                *(u16x4*)(Aout  + (size_t)xrow * CDIM + t * 16 + q * 4) = oa;
                *(u16x4*)(Bout  + (size_t)xrow * CDIM + t * 16 + q * 4) = ob;
                *(u16x4*)(Rbout + (size_t)xrow * CDIM + t * 16 + q * 4) = orr;
            }
        }
    }
}

// ======================= CSR build (once per launch) =======================
__global__ __launch_bounds__(256)
void hist_dst(const int* __restrict__ dst, int* __restrict__ cnt, int n) {
    int e = blockIdx.x * 256 + threadIdx.x;
    if (e < n) atomicAdd(&cnt[clampi(dst[e], N_NODES)], 1);
}

__global__ __launch_bounds__(256)
void scan_local(const int* __restrict__ cnt, int* __restrict__ incl,
                int* __restrict__ blockSums, int n) {
    __shared__ int lds[256];
    int t = threadIdx.x;
    int base = blockIdx.x * SCAN_CHUNK + t * 4;
    int v[4], s = 0;
#pragma unroll
    for (int j = 0; j < 4; ++j) { v[j] = (base + j < n) ? cnt[base + j] : 0; s += v[j]; }
    lds[t] = s;
    __syncthreads();
    for (int off = 1; off < 256; off <<= 1) {
        int x = (t >= off) ? lds[t - off] : 0;
        __syncthreads();
        lds[t] += x;
        __syncthreads();
    }
    int run = lds[t] - s;
#pragma unroll
    for (int j = 0; j < 4; ++j) {
        run += v[j];
        if (base + j < n) incl[base + j] = run;
    }
    if (t == 255) blockSums[blockIdx.x] = lds[255];
}

__global__ __launch_bounds__(128)
void scan_sums(int* __restrict__ blockSums, int nb) {
    __shared__ int lds[128];
    int t = threadIdx.x;
    int v = (t < nb) ? blockSums[t] : 0;
    lds[t] = v;
    __syncthreads();
    for (int off = 1; off < 128; off <<= 1) {
        int x = (t >= off) ? lds[t - off] : 0;
        __syncthreads();
        lds[t] += x;
        __syncthreads();
    }
    if (t < nb) blockSums[t] = lds[t] - v;   // exclusive
}

__global__ __launch_bounds__(256)
void add_offsets(const int* __restrict__ incl, const int* __restrict__ blockSums,
                 const int* __restrict__ cnt, int* __restrict__ rowptr,
                 int* __restrict__ cursor, int n) {
    int i = blockIdx.x * 256 + threadIdx.x;
    if (i < n) {
        int v = incl[i] + blockSums[i / SCAN_CHUNK];
        rowptr[i + 1] = v;
        cursor[i] = v - cnt[i];
    }
    if (i == 0) rowptr[0] = 0;
}

__global__ __launch_bounds__(256)
void scatter_edges(const int* __restrict__ src, const int* __restrict__ dst,
                   int* __restrict__ cursor, int* __restrict__ esrc, int n) {
    int e = blockIdx.x * 256 + threadIdx.x;
    if (e < n) {
        int d = clampi(dst[e], N_NODES);
        int p = atomicAdd(&cursor[d], 1);
        esrc[p] = clampi(src[e], N_NODES);
    }
}

// ======================= fused edge phase =======================
// One wave per dst node; 2 ch/lane. den = sum exp(e); acc = sum exp(e)*xl[src].
// 4-edge unroll: four independent shuffle chains interleaved (latency hiding).
// Epilogue: Out[d] = relu(Rb[d] + acc/den), Rb bf16. BF16OUT: Out bf16 else fp32.
template <bool BF16OUT>
__global__ __launch_bounds__(256)
void fused_edge(const int* __restrict__ rowptr, const int* __restrict__ esrc,
                const unsigned short* __restrict__ A,
                const unsigned short* __restrict__ B,
                const float* __restrict__ att,
                const unsigned short* __restrict__ Rb, void* __restrict__ Outv,
                int n_nodes) {
    const int wave = threadIdx.x >> 6;
    const int lane = threadIdx.x & 63;
    const int d = blockIdx.x * 4 + wave;
    if (d >= n_nodes) return;
    const int c0 = lane * 2;

    unsigned int ub = *(const unsigned int*)(B + (size_t)d * CDIM + c0);
    const float b0 = bf2f((unsigned short)(ub & 0xffff));
    const float b1 = bf2f((unsigned short)(ub >> 16));
    const float at0 = att[c0];
    const float at1 = att[c0 + 1];

    float acc0 = 0.0f, acc1 = 0.0f, den = 0.0f;
    const int p0 = rowptr[d], p1 = rowptr[d + 1];
    int p = p0;
    for (; p + 4 <= p1; p += 4) {
        float a0[4], a1[4], e[4];
#pragma unroll
        for (int u = 0; u < 4; ++u) {
            int s = esrc[p + u];
            unsigned int ua = *(const unsigned int*)(A + (size_t)s * CDIM + c0);
            a0[u] = bf2f((unsigned short)(ua & 0xffff));
            a1[u] = bf2f((unsigned short)(ua >> 16));
            e[u] = lrelu(a0[u] + b0) * at0 + lrelu(a1[u] + b1) * at1;
        }
#pragma unroll
        for (int off = 32; off >= 1; off >>= 1) {
#pragma unroll
            for (int u = 0; u < 4; ++u) e[u] += __shfl_xor(e[u], off, 64);
        }
#pragma unroll
        for (int u = 0; u < 4; ++u) {
            float ee = __expf(fminf(e[u], 60.0f));   // |e| analytically << 60
            den  += ee;
            acc0 += ee * a0[u];
            acc1 += ee * a1[u];
        }
    }
    for (; p < p1; ++p) {
        int s = esrc[p];
        unsigned int ua = *(const unsigned int*)(A + (size_t)s * CDIM + c0);
        float a00 = bf2f((unsigned short)(ua & 0xffff));
        float a01 = bf2f((unsigned short)(ua >> 16));
        float e0 = lrelu(a00 + b0) * at0 + lrelu(a01 + b1) * at1;
#pragma unroll
        for (int off = 32; off >= 1; off >>= 1) e0 += __shfl_xor(e0, off, 64);
        float ee0 = __expf(fminf(e0, 60.0f));
        den  += ee0;
        acc0 += ee0 * a00;
        acc1 += ee0 * a01;
    }

    float inv = 1.0f / fmaxf(den, 1e-16f);
    unsigned int rr = *(const unsigned int*)(Rb + (size_t)d * CDIM + c0);
    float o0 = fmaxf(bf2f((unsigned short)(rr & 0xffff)) + acc0 * inv, 0.0f);
    float o1 = fmaxf(bf2f((unsigned short)(rr >> 16))    + acc1 * inv, 0.0f);
    if (BF16OUT) {
        unsigned int pk = (unsigned int)f2bf(o0) | ((unsigned int)f2bf(o1) << 16);
        *(unsigned int*)((unsigned short*)Outv + (size_t)d * CDIM + c0) = pk;
    } else {
        *(float2*)((float*)Outv + (size_t)d * CDIM + c0) = make_float2(o0, o1);
    }
}

extern "C" void kernel_launch(void* const* d_in, const int* in_sizes, int n_in,
                              void* d_out, int out_size, void* d_ws, size_t ws_size,
                              hipStream_t stream) {
    const float* x     = (const float*)d_in[0];
    const int*   ei    = (const int*)d_in[1];
    const float* Wl1   = (const float*)d_in[2];
    const float* Wr1   = (const float*)d_in[3];
    const float* att1  = (const float*)d_in[4];
    const float* Wres1 = (const float*)d_in[5];
    const float* b1    = (const float*)d_in[6];
    const float* Wl2   = (const float*)d_in[7];
    const float* Wr2   = (const float*)d_in[8];
    const float* att2  = (const float*)d_in[9];
    const float* Wres2 = (const float*)d_in[10];
    const float* b2    = (const float*)d_in[11];

    const int* srcp = ei;
    const int* dstp = ei + E_EDGES;

    // ---- workspace carve (~109 MB) ----
    size_t off = 0;
    char* base = (char*)d_ws;
    auto carve = [&](size_t bytes) -> void* {
        void* q = base + off;
        off += (bytes + 255) & ~(size_t)255;
        return q;
    };
    unsigned short* Wf = (unsigned short*)carve((size_t)6 * 16384 * 2);        // 192 KB
    unsigned short* A  = (unsigned short*)carve((size_t)N_NODES * CDIM * 2);   // 25.6 MB
    unsigned short* B  = (unsigned short*)carve((size_t)N_NODES * CDIM * 2);   // 25.6 MB
    unsigned short* X1 = (unsigned short*)carve((size_t)N_NODES * CDIM * 2);   // 25.6 MB
    unsigned short* Rb = (unsigned short*)carve((size_t)N_NODES * CDIM * 2);   // 25.6 MB
    int* cnt      = (int*)carve((size_t)N_NODES * 4);
    int* rowptr   = (int*)carve((size_t)(N_NODES + 1) * 4);
    int* cursor   = (int*)carve((size_t)N_NODES * 4);
    int* esrc     = (int*)carve((size_t)E_EDGES * 4);
    int* incl     = (int*)carve((size_t)N_NODES * 4);
    int* blockSums= (int*)carve((size_t)SCAN_NB * 4);
    (void)ws_size; (void)n_in; (void)in_sizes; (void)out_size;

    // ---- weight prep: all 6 mats, one launch ----
    pack_w_all<<<48, 256, 0, stream>>>(Wl1, Wr1, Wres1, Wl2, Wr2, Wres2, Wf);

    // ---- CSR build (dst-grouped), reused by both layers ----
    (void)hipMemsetAsync(cnt, 0, (size_t)N_NODES * 4, stream);
    hist_dst<<<(E_EDGES + 255) / 256, 256, 0, stream>>>(dstp, cnt, E_EDGES);
    scan_local<<<SCAN_NB, 256, 0, stream>>>(cnt, incl, blockSums, N_NODES);
    scan_sums<<<1, 128, 0, stream>>>(blockSums, SCAN_NB);
    add_offsets<<<(N_NODES + 255) / 256, 256, 0, stream>>>(incl, blockSums, cnt,
                                                           rowptr, cursor, N_NODES);
    scatter_edges<<<(E_EDGES + 255) / 256, 256, 0, stream>>>(srcp, dstp, cursor,
                                                             esrc, E_EDGES);

    int egrid = (N_NODES + 3) / 4;

    // layer 1: X=x (fp32, split) -> A,B,Rb; fused_edge -> X1 (bf16)
    projF<true ><<<256, 512, 0, stream>>>(x, Wf, b1, A, B, Rb, N_NODES);
    fused_edge<true ><<<egrid, 256, 0, stream>>>(rowptr, esrc, A, B, att1, Rb, X1, N_NODES);
    // layer 2: X=X1 (bf16, no split) -> A,B,Rb; fused_edge -> d_out (fp32)
    projF<false><<<256, 512, 0, stream>>>(X1, Wf + (size_t)3 * 16384, b2, A, B, Rb, N_NODES);
    fused_edge<false><<<egrid, 256, 0, stream>>>(rowptr, esrc, A, B, att2, Rb, d_out, N_NODES);
}

// Round 11
// 349.026 us; speedup vs baseline: 3.1194x; 2.0530x over previous
//
#include <hip/hip_runtime.h>
#include <math.h>

#define N_NODES 100000
#define CDIM 128
#define E_EDGES 500000
#define NEG_SLOPE 0.2f
#define SCAN_CHUNK 1024   // 256 threads x 4 items
#define SCAN_NB ((N_NODES + SCAN_CHUNK - 1) / SCAN_CHUNK)   // 98
#define NSTRIP64 ((N_NODES + 63) / 64)                      // 1563

typedef __attribute__((ext_vector_type(8))) short short8;             // 8 bf16 (MFMA frag)
typedef __attribute__((ext_vector_type(8))) unsigned short ushort8;
typedef __attribute__((ext_vector_type(4))) unsigned short u16x4;
typedef __attribute__((ext_vector_type(4))) float f32x4;

static __device__ __forceinline__ float bf2f(unsigned short u) {
    unsigned int t = ((unsigned int)u) << 16;
    return __builtin_bit_cast(float, t);
}
static __device__ __forceinline__ unsigned short f2bf(float f) {
    unsigned int u = __builtin_bit_cast(unsigned int, f);
    unsigned int r = (u + 0x7FFFu + ((u >> 16) & 1u)) >> 16;   // RNE
    return (unsigned short)r;
}
static __device__ __forceinline__ int clampi(int v, int hi) {
    return v < 0 ? 0 : (v >= hi ? hi - 1 : v);
}
static __device__ __forceinline__ float lrelu(float v) {
    return v > 0.0f ? v : NEG_SLOPE * v;
}

// ---- pack all 6 fp32 128x128 W into MFMA-fragment-major bf16 ----
// chunk(kk,t): lane l (m=l&15,q=l>>4) owns W[kk*32+q*8+u][t*16+m], u=0..7.
__global__ __launch_bounds__(256)
void pack_w_all(const float* __restrict__ W0, const float* __restrict__ W1,
                const float* __restrict__ W2, const float* __restrict__ W3,
                const float* __restrict__ W4, const float* __restrict__ W5,
                unsigned short* __restrict__ Wf) {
    const float* Wp[6] = {W0, W1, W2, W3, W4, W5};
    int mi  = blockIdx.x >> 3;                       // 0..5 (block-uniform)
    int rem = ((blockIdx.x & 7) << 8) | threadIdx.x; // 0..2047
    const float* W = Wp[mi];
    int l = rem & 63, t = (rem >> 6) & 7, kk = rem >> 9;
    int m = l & 15, q = l >> 4;
    int j = t * 16 + m;
    int k0 = kk * 32 + q * 8;
    ushort8 o;
#pragma unroll
    for (int u = 0; u < 8; ++u) o[u] = f2bf(W[(k0 + u) * 128 + j]);
    *(ushort8*)(Wf + ((size_t)mi * 2048 + rem) * 8) = o;
}

// ---- fused 3-matrix projection, t-split for low register pressure:
// A=bf16(X@Wl), B=bf16(X@Wr), Rb=bf16(X@Wres+bias)
// Two passes over output-column halves: live acc = [3][4] f32x4 = 48 regs (NOT 96 —
// rounds 9/10 proved acc[3][8]+staging spills at every config). No LDS; W frags via
// L1/L2. 256 threads, __launch_bounds__(256,4): VGPR cap 128, need ~90 -> no spill,
// ~4 waves/SIMD to hide W-load latency.
// a-op = W frag, b-op = X frag -> lane owns out[row0+lane%16][t*16+q*4+r] (wide stores).
// XSPLIT: X fp32 hi/lo split (fp32-accurate). !XSPLIT: X bf16 (half MFMAs).
template <bool XSPLIT>
__global__ __launch_bounds__(256, 4)
void projF(const void* __restrict__ Xv,
           const unsigned short* __restrict__ Wf,    // 3 mats, frag-major
           const float* __restrict__ bias,
           unsigned short* __restrict__ Aout,
           unsigned short* __restrict__ Bout,
           unsigned short* __restrict__ Rbout, int n_rows) {
    const int wave = threadIdx.x >> 6;
    const int lane = threadIdx.x & 63;
    const int m = lane & 15, q = lane >> 4;
    const int row0 = blockIdx.x * 64 + wave * 16;
    const int xrow = row0 + m;                     // this lane's output row
    const int arow = xrow < n_rows ? xrow : n_rows - 1;

#pragma unroll
    for (int h = 0; h < 2; ++h) {                  // output-column half
        f32x4 acc[3][4];
#pragma unroll
        for (int mi = 0; mi < 3; ++mi)
#pragma unroll
            for (int t = 0; t < 4; ++t) acc[mi][t] = (f32x4)0.0f;

#pragma unroll
        for (int kk = 0; kk < 4; ++kk) {
            short8 xh, xl_;
            if (XSPLIT) {
                const float* xp = (const float*)Xv + (size_t)arow * CDIM + kk * 32 + q * 8;
                f32x4 x0 = *(const f32x4*)xp;
                f32x4 x1 = *(const f32x4*)(xp + 4);
#pragma unroll
                for (int j = 0; j < 4; ++j) {
                    unsigned short h0 = f2bf(x0[j]);
                    xh[j] = (short)h0;
                    xl_[j] = (short)f2bf(x0[j] - bf2f(h0));
                    unsigned short h1 = f2bf(x1[j]);
                    xh[4 + j] = (short)h1;
                    xl_[4 + j] = (short)f2bf(x1[j] - bf2f(h1));
                }
            } else {
                xh = *(const short8*)((const unsigned short*)Xv +
                                      (size_t)arow * CDIM + kk * 32 + q * 8);
            }
#pragma unroll
            for (int tt = 0; tt < 4; ++tt) {
                const int t = h * 4 + tt;
                const size_t fo = ((size_t)(kk * 8 + t) * 64 + lane) * 8;
                short8 w0 = *(const short8*)(Wf + fo);
                short8 w1 = *(const short8*)(Wf + 16384 + fo);
                short8 w2 = *(const short8*)(Wf + 32768 + fo);
                acc[0][tt] = __builtin_amdgcn_mfma_f32_16x16x32_bf16(w0, xh, acc[0][tt], 0, 0, 0);
                acc[1][tt] = __builtin_amdgcn_mfma_f32_16x16x32_bf16(w1, xh, acc[1][tt], 0, 0, 0);
                acc[2][tt] = __builtin_amdgcn_mfma_f32_16x16x32_bf16(w2, xh, acc[2][tt], 0, 0, 0);
                if (XSPLIT) {
                    acc[0][tt] = __builtin_amdgcn_mfma_f32_16x16x32_bf16(w0, xl_, acc[0][tt], 0, 0, 0);
                    acc[1][tt] = __builtin_amdgcn_mfma_f32_16x16x32_bf16(w1, xl_, acc[1][tt], 0, 0, 0);
                    acc[2][tt] = __builtin_amdgcn_mfma_f32_16x16x32_bf16(w2, xl_, acc[2][tt], 0, 0, 0);
                }
            }
        }

        if (xrow < n_rows) {
#pragma unroll
            for (int tt = 0; tt < 4; ++tt) {
                const int t = h * 4 + tt;
                u16x4 oa, ob, orr;
                f32x4 bv = *(const f32x4*)(bias + t * 16 + q * 4);
#pragma unroll
                for (int r = 0; r < 4; ++r) {
                    oa[r] = f2bf(acc[0][tt][r]);
                    ob[r] = f2bf(acc[1][tt][r]);
                    orr[r] = f2bf(acc[2][tt][r] + bv[r]);
                }
                *(u16x4*)(Aout  + (size_t)xrow * CDIM + t * 16 + q * 4) = oa;
                *(u16x4*)(Bout  + (size_t)xrow * CDIM + t * 16 + q * 4) = ob;
                *(u16x4*)(Rbout + (size_t)xrow * CDIM + t * 16 + q * 4) = orr;
            }
        }
    }
}

// ======================= CSR build (once per launch) =======================
__global__ __launch_bounds__(256)
void hist_dst(const int* __restrict__ dst, int* __restrict__ cnt, int n) {
    int e = blockIdx.x * 256 + threadIdx.x;
    if (e < n) atomicAdd(&cnt[clampi(dst[e], N_NODES)], 1);
}

__global__ __launch_bounds__(256)
void scan_local(const int* __restrict__ cnt, int* __restrict__ incl,
                int* __restrict__ blockSums, int n) {
    __shared__ int lds[256];
    int t = threadIdx.x;
    int base = blockIdx.x * SCAN_CHUNK + t * 4;
    int v[4], s = 0;
#pragma unroll
    for (int j = 0; j < 4; ++j) { v[j] = (base + j < n) ? cnt[base + j] : 0; s += v[j]; }
    lds[t] = s;
    __syncthreads();
    for (int off = 1; off < 256; off <<= 1) {
        int x = (t >= off) ? lds[t - off] : 0;
        __syncthreads();
        lds[t] += x;
        __syncthreads();
    }
    int run = lds[t] - s;
#pragma unroll
    for (int j = 0; j < 4; ++j) {
        run += v[j];
        if (base + j < n) incl[base + j] = run;
    }
    if (t == 255) blockSums[blockIdx.x] = lds[255];
}

__global__ __launch_bounds__(128)
void scan_sums(int* __restrict__ blockSums, int nb) {
    __shared__ int lds[128];
    int t = threadIdx.x;
    int v = (t < nb) ? blockSums[t] : 0;
    lds[t] = v;
    __syncthreads();
    for (int off = 1; off < 128; off <<= 1) {
        int x = (t >= off) ? lds[t - off] : 0;
        __syncthreads();
        lds[t] += x;
        __syncthreads();
    }
    if (t < nb) blockSums[t] = lds[t] - v;   // exclusive
}

__global__ __launch_bounds__(256)
void add_offsets(const int* __restrict__ incl, const int* __restrict__ blockSums,
                 const int* __restrict__ cnt, int* __restrict__ rowptr,
                 int* __restrict__ cursor, int n) {
    int i = blockIdx.x * 256 + threadIdx.x;
    if (i < n) {
        int v = incl[i] + blockSums[i / SCAN_CHUNK];
        rowptr[i + 1] = v;
        cursor[i] = v - cnt[i];
    }
    if (i == 0) rowptr[0] = 0;
}

__global__ __launch_bounds__(256)
void scatter_edges(const int* __restrict__ src, const int* __restrict__ dst,
                   int* __restrict__ cursor, int* __restrict__ esrc, int n) {
    int e = blockIdx.x * 256 + threadIdx.x;
    if (e < n) {
        int d = clampi(dst[e], N_NODES);
        int p = atomicAdd(&cursor[d], 1);
        esrc[p] = clampi(src[e], N_NODES);
    }
}

// ======================= fused edge phase =======================
// 4 nodes per wave: 16-lane group per node, 8 channels per lane.
// Per edge: one ushort8 gather (16B/lane), ~30 VALU, FOUR segment shuffles
// (width 16) -- and all 4 groups reduce their own edges in the SAME wave instr,
// vs round-10's 6 wave-wide shuffles per single edge. den/acc accumulated per
// lane; epilogue Out[d] = relu(Rb[d] + acc/den).  BF16OUT: Out bf16 else fp32.
template <bool BF16OUT>
__global__ __launch_bounds__(256)
void fused_edge(const int* __restrict__ rowptr, const int* __restrict__ esrc,
                const unsigned short* __restrict__ A,
                const unsigned short* __restrict__ B,
                const float* __restrict__ att,
                const unsigned short* __restrict__ Rb, void* __restrict__ Outv,
                int n_nodes) {
    const int wave = threadIdx.x >> 6;
    const int lane = threadIdx.x & 63;
    const int g    = lane >> 4;               // group 0..3 within wave
    const int i    = lane & 15;
    const int d    = (blockIdx.x * 4 + wave) * 4 + g;   // 16 nodes per block
    const bool valid = d < n_nodes;
    const int dd = valid ? d : n_nodes - 1;
    const int c0 = i * 8;

    ushort8 ub = *(const ushort8*)(B + (size_t)dd * CDIM + c0);
    float b[8], at[8];
    f32x4 at0 = *(const f32x4*)(att + c0);
    f32x4 at1 = *(const f32x4*)(att + c0 + 4);
#pragma unroll
    for (int j = 0; j < 4; ++j) {
        b[j] = bf2f(ub[j]);   b[4 + j] = bf2f(ub[4 + j]);
        at[j] = at0[j];       at[4 + j] = at1[j];
    }

    float acc[8] = {0, 0, 0, 0, 0, 0, 0, 0};
    float den = 0.0f;
    int p  = rowptr[dd];
    int p1 = valid ? rowptr[dd + 1] : p;

    for (; p < p1; ++p) {
        int s = esrc[p];
        ushort8 ua = *(const ushort8*)(A + (size_t)s * CDIM + c0);
        float a[8];
        float e = 0.0f;
#pragma unroll
        for (int j = 0; j < 8; ++j) {
            a[j] = bf2f(ua[j]);
            e += lrelu(a[j] + b[j]) * at[j];
        }
#pragma unroll
        for (int off = 8; off >= 1; off >>= 1) e += __shfl_xor(e, off, 16);
        float ee = __expf(fminf(e, 60.0f));   // |e| analytically << 60; clamp = armor
        den += ee;
#pragma unroll
        for (int j = 0; j < 8; ++j) acc[j] += ee * a[j];
    }

    if (valid) {
        float inv = 1.0f / fmaxf(den, 1e-16f);
        ushort8 rr = *(const ushort8*)(Rb + (size_t)d * CDIM + c0);
        float o[8];
#pragma unroll
        for (int j = 0; j < 8; ++j)
            o[j] = fmaxf(bf2f(rr[j]) + acc[j] * inv, 0.0f);
        if (BF16OUT) {
            ushort8 pk;
#pragma unroll
            for (int j = 0; j < 8; ++j) pk[j] = f2bf(o[j]);
            *(ushort8*)((unsigned short*)Outv + (size_t)d * CDIM + c0) = pk;
        } else {
            f32x4 o0, o1;
#pragma unroll
            for (int j = 0; j < 4; ++j) { o0[j] = o[j]; o1[j] = o[4 + j]; }
            float* op = (float*)Outv + (size_t)d * CDIM + c0;
            *(f32x4*)op = o0;
            *(f32x4*)(op + 4) = o1;
        }
    }
}

extern "C" void kernel_launch(void* const* d_in, const int* in_sizes, int n_in,
                              void* d_out, int out_size, void* d_ws, size_t ws_size,
                              hipStream_t stream) {
    const float* x     = (const float*)d_in[0];
    const int*   ei    = (const int*)d_in[1];
    const float* Wl1   = (const float*)d_in[2];
    const float* Wr1   = (const float*)d_in[3];
    const float* att1  = (const float*)d_in[4];
    const float* Wres1 = (const float*)d_in[5];
    const float* b1    = (const float*)d_in[6];
    const float* Wl2   = (const float*)d_in[7];
    const float* Wr2   = (const float*)d_in[8];
    const float* att2  = (const float*)d_in[9];
    const float* Wres2 = (const float*)d_in[10];
    const float* b2    = (const float*)d_in[11];

    const int* srcp = ei;
    const int* dstp = ei + E_EDGES;

    // ---- workspace carve (~109 MB) ----
    size_t off = 0;
    char* base = (char*)d_ws;
    auto carve = [&](size_t bytes) -> void* {
        void* q = base + off;
        off += (bytes + 255) & ~(size_t)255;
        return q;
    };
    unsigned short* Wf = (unsigned short*)carve((size_t)6 * 16384 * 2);        // 192 KB
    unsigned short* A  = (unsigned short*)carve((size_t)N_NODES * CDIM * 2);   // 25.6 MB
    unsigned short* B  = (unsigned short*)carve((size_t)N_NODES * CDIM * 2);   // 25.6 MB
    unsigned short* X1 = (unsigned short*)carve((size_t)N_NODES * CDIM * 2);   // 25.6 MB
    unsigned short* Rb = (unsigned short*)carve((size_t)N_NODES * CDIM * 2);   // 25.6 MB
    int* cnt      = (int*)carve((size_t)N_NODES * 4);
    int* rowptr   = (int*)carve((size_t)(N_NODES + 1) * 4);
    int* cursor   = (int*)carve((size_t)N_NODES * 4);
    int* esrc     = (int*)carve((size_t)E_EDGES * 4);
    int* incl     = (int*)carve((size_t)N_NODES * 4);
    int* blockSums= (int*)carve((size_t)SCAN_NB * 4);
    (void)ws_size; (void)n_in; (void)in_sizes; (void)out_size;

    // ---- weight prep: all 6 mats, one launch ----
    pack_w_all<<<48, 256, 0, stream>>>(Wl1, Wr1, Wres1, Wl2, Wr2, Wres2, Wf);

    // ---- CSR build (dst-grouped), reused by both layers ----
    (void)hipMemsetAsync(cnt, 0, (size_t)N_NODES * 4, stream);
    hist_dst<<<(E_EDGES + 255) / 256, 256, 0, stream>>>(dstp, cnt, E_EDGES);
    scan_local<<<SCAN_NB, 256, 0, stream>>>(cnt, incl, blockSums, N_NODES);
    scan_sums<<<1, 128, 0, stream>>>(blockSums, SCAN_NB);
    add_offsets<<<(N_NODES + 255) / 256, 256, 0, stream>>>(incl, blockSums, cnt,
                                                           rowptr, cursor, N_NODES);
    scatter_edges<<<(E_EDGES + 255) / 256, 256, 0, stream>>>(srcp, dstp, cursor,
                                                             esrc, E_EDGES);

    int egrid = (N_NODES + 15) / 16;   // 16 nodes per block (4 waves x 4 groups)

    // layer 1: X=x (fp32, split) -> A,B,Rb; fused_edge -> X1 (bf16)
    projF<true ><<<NSTRIP64, 256, 0, stream>>>(x, Wf, b1, A, B, Rb, N_NODES);
    fused_edge<true ><<<egrid, 256, 0, stream>>>(rowptr, esrc, A, B, att1, Rb, X1, N_NODES);
    // layer 2: X=X1 (bf16, no split) -> A,B,Rb; fused_edge -> d_out (fp32)
    projF<false><<<NSTRIP64, 256, 0, stream>>>(X1, Wf + (size_t)3 * 16384, b2, A, B, Rb, N_NODES);
    fused_edge<false><<<egrid, 256, 0, stream>>>(rowptr, esrc, A, B, att2, Rb, d_out, N_NODES);
}